// Round 3
// baseline (989.564 us; speedup 1.0000x reference)
//
#include <hip/hip_runtime.h>
#include <hip/hip_bf16.h>
#include <hip/hip_cooperative_groups.h>

namespace cg = cooperative_groups;

// Problem constants (fixed by the reference):
#define E_EDGES 640000
#define DIM     128
#define N_NODES 40000

#define PREP_BLOCKS 1280
#define PREP_THREADS (PREP_BLOCKS * 256)

#define GEMM_BLOCKS 1024
#define NWAVES_TOT  (GEMM_BLOCKS * 4)   // 4096 waves, ~10 nodes each

typedef __bf16 bf16x8 __attribute__((ext_vector_type(8)));
typedef float  floatx4 __attribute__((ext_vector_type(4)));

// ---------------------------------------------------------------------------
// Fused prep (cooperative): zero cnt + swizzle W -> hist -> scan -> scatter.
// Wsw[((nb*4+kb)*64 + lane)*8 + j] = W[nb*16 + (lane&15)][kb*32 + (lane>>4)*8 + j]
// ---------------------------------------------------------------------------
__device__ __forceinline__ void swizzle_w(const float* __restrict__ W,
                                          __bf16* __restrict__ Wsw, int tid) {
    int lane = tid & 63;
    int kb   = (tid >> 6) & 3;
    int nb   = tid >> 8;
    int f    = nb * 16 + (lane & 15);
    int k0   = kb * 32 + ((lane >> 4) & 3) * 8;
    const float* wrow = W + f * DIM + k0;
    __bf16* o = Wsw + tid * 8;
#pragma unroll
    for (int j = 0; j < 8; ++j) o[j] = (__bf16)wrow[j];
}

__global__ __launch_bounds__(256)
void prep_all(const float* __restrict__ W, const int* __restrict__ dst,
              __bf16* __restrict__ Wsw, int* __restrict__ cnt,
              int* __restrict__ starts, int* __restrict__ perm) {
    cg::grid_group grid = cg::this_grid();
    __shared__ int ssum[256];
    const int tid = blockIdx.x * 256 + threadIdx.x;

    // phase 0: zero counters + swizzle W
    for (int i = tid; i < N_NODES; i += PREP_THREADS) cnt[i] = 0;
    if (tid < 2048) swizzle_w(W, Wsw, tid);
    grid.sync();

    // phase 1: histogram of destination nodes
    for (int e = tid; e < E_EDGES; e += PREP_THREADS) atomicAdd(&cnt[dst[e]], 1);
    grid.sync();

    // phase 2: exclusive scan cnt -> starts (block 0 only; 256 x 157 >= 40000)
    if (blockIdx.x == 0) {
        const int t = threadIdx.x;
        const int base = t * 157;
        int local = 0;
        for (int i = 0; i < 157; ++i) {
            int idx = base + i;
            if (idx < N_NODES) local += cnt[idx];
        }
        ssum[t] = local;
        __syncthreads();
        for (int off = 1; off < 256; off <<= 1) {
            int v = (t >= off) ? ssum[t - off] : 0;
            __syncthreads();
            ssum[t] += v;
            __syncthreads();
        }
        int run = ssum[t] - local;
        for (int i = 0; i < 157; ++i) {
            int idx = base + i;
            if (idx < N_NODES) { starts[idx] = run; run += cnt[idx]; }
        }
    }
    grid.sync();

    // phase 3: scatter edge ids into per-node runs (starts -> ends)
    for (int e = tid; e < E_EDGES; e += PREP_THREADS) {
        int pos = atomicAdd(&starts[dst[e]], 1);
        perm[pos] = e;
    }
}

// --------------------- fallback (non-cooperative) prep ---------------------
__global__ void prep_kernel(const float* __restrict__ W,
                            __bf16* __restrict__ Wsw,
                            int* __restrict__ cnt) {
    int tid = blockIdx.x * blockDim.x + threadIdx.x;
    if (tid < N_NODES) cnt[tid] = 0;
    if (tid < 2048) swizzle_w(W, Wsw, tid);
}
__global__ void hist_kernel(const int* __restrict__ dst, int* __restrict__ cnt) {
    int e = blockIdx.x * 256 + threadIdx.x;
    atomicAdd(&cnt[dst[e]], 1);
}
__global__ __launch_bounds__(1024)
void scan_kernel(const int* __restrict__ cnt, int* __restrict__ starts) {
    __shared__ int ss[1024];
    const int t = threadIdx.x;
    const int base = t * 40;
    int local = 0;
    for (int i = 0; i < 40; ++i) {
        int idx = base + i;
        if (idx < N_NODES) local += cnt[idx];
    }
    ss[t] = local;
    __syncthreads();
    for (int off = 1; off < 1024; off <<= 1) {
        int v = (t >= off) ? ss[t - off] : 0;
        __syncthreads();
        ss[t] += v;
        __syncthreads();
    }
    int run = ss[t] - local;
    for (int i = 0; i < 40; ++i) {
        int idx = base + i;
        if (idx < N_NODES) { starts[idx] = run; run += cnt[idx]; }
    }
}
__global__ void scatter_kernel(const int* __restrict__ dst,
                               int* __restrict__ starts,
                               int* __restrict__ perm) {
    int e = blockIdx.x * 256 + threadIdx.x;
    int pos = atomicAdd(&starts[dst[e]], 1);
    perm[pos] = e;
}

// ---------------------------------------------------------------------------
// Main kernel helpers
// ---------------------------------------------------------------------------
__device__ __forceinline__ void load_convert(bf16x8 (&af)[4], const float* arow) {
#pragma unroll
    for (int kb = 0; kb < 4; ++kb) {
        float4 a0 = *(const float4*)(arow + kb * 32);
        float4 a1 = *(const float4*)(arow + kb * 32 + 4);
        af[kb][0] = (__bf16)a0.x; af[kb][1] = (__bf16)a0.y;
        af[kb][2] = (__bf16)a0.z; af[kb][3] = (__bf16)a0.w;
        af[kb][4] = (__bf16)a1.x; af[kb][5] = (__bf16)a1.y;
        af[kb][6] = (__bf16)a1.z; af[kb][7] = (__bf16)a1.w;
    }
}

__device__ __forceinline__ void mfma_tile(const bf16x8 (&af)[4],
                                          const bf16x8* __restrict__ Wl,
                                          floatx4 (&acc)[8], int lane) {
#pragma unroll
    for (int kb = 0; kb < 4; ++kb)
#pragma unroll
        for (int nb = 0; nb < 8; ++nb)
            acc[nb] = __builtin_amdgcn_mfma_f32_16x16x32_bf16(
                af[kb], Wl[(nb * 4 + kb) * 64 + lane], acc[nb], 0, 0, 0);
}

__device__ __forceinline__ void reduce_store(floatx4 (&vm)[8],
                                             const float* __restrict__ bias,
                                             float* __restrict__ orow,
                                             int q, int lane) {
    float red[8];
#pragma unroll
    for (int nb = 0; nb < 8; ++nb) {
        float v = fmaxf(fmaxf(vm[nb][0], vm[nb][1]), fmaxf(vm[nb][2], vm[nb][3]));
        v = fmaxf(v, __shfl_xor(v, 16));
        v = fmaxf(v, __shfl_xor(v, 32));
        red[nb] = v;
    }
    float o1 = (q == 0) ? red[0] : (q == 1) ? red[1] : (q == 2) ? red[2] : red[3];
    float o2 = (q == 0) ? red[4] : (q == 1) ? red[5] : (q == 2) ? red[6] : red[7];
    // bias-add and relu commute with max (bias per-column, relu monotone)
    orow[lane]      = fmaxf(o1 + bias[lane],      0.0f);
    orow[lane + 64] = fmaxf(o2 + bias[lane + 64], 0.0f);
}

// ---------------------------------------------------------------------------
// Persistent main kernel: 4096 waves, each owns nodes g, g+4096, ...
// Per node: chunk0 (rows 0..15) + chunk1 (rows 16..31) unrolled, rare c>32
// tail loop. Next node's cnt/ends/perm prefetched under current node's MFMA.
// Zero atomics; one coalesced 512B store per node.
// NOTE (R2 bug fix): chunk-1 row mask r1c is recomputed from the CURRENT
// node's c every iteration — R2 carried a stale prologue-only r1.
// A-frag:  A[m=lane&15][k=q*8+j]   (gathered rows, 16B loads)
// B-frag:  B[k=q*8+j][n=lane&15]   (pre-swizzled, staged once in LDS)
// C/D:     col=lane&15, row=q*4+reg
// ---------------------------------------------------------------------------
__global__ __launch_bounds__(256)
void node_gemm_kernel(const float* __restrict__ src,
                      const __bf16* __restrict__ Wsw,
                      const float* __restrict__ bias,
                      const int* __restrict__ perm,
                      const int* __restrict__ cnt,
                      const int* __restrict__ ends,
                      float* __restrict__ out) {
    __shared__ bf16x8 Wl[2048];   // 32 KB swizzled W, staged once per block
    const int t = threadIdx.x;
    {
        const float4* gw = (const float4*)Wsw;
        float4* lw = (float4*)Wl;
#pragma unroll
        for (int i = 0; i < 8; ++i) lw[t + i * 256] = gw[t + i * 256];
    }
    __syncthreads();

    const int lane = t & 63;
    const int wave = t >> 6;
    const int q    = lane >> 4;
    const int n    = lane & 15;

    int node = blockIdx.x * 4 + wave;            // 0..4095 < N_NODES

    // prologue: metadata + chunk0/1 gather indices for first node
    int c  = cnt[node];
    int st = ends[node] - c;
    {
        int r0 = c < 16 ? c : 16;
        int r1 = (c > 16) ? ((c < 32 ? c : 32) - 16) : 0;
        // ea/eb assigned below via the same pattern as the loop's prefetch
        (void)r0; (void)r1;
    }
    int ea, eb;
    {
        int r0 = c < 16 ? c : 16;
        ea = (n < r0) ? perm[st + n] : 0;
        int r1 = (c > 16) ? ((c < 32 ? c : 32) - 16) : 0;
        eb = (n < r1) ? perm[st + 16 + n] : 0;
    }

    while (true) {
        const int nnode = node + NWAVES_TOT;
        const bool hn = nnode < N_NODES;
        int c2 = 0, st2 = 0, ea2 = 0, eb2 = 0;
        if (hn) {                                 // issue next metadata early
            c2  = cnt[nnode];
            st2 = ends[nnode] - c2;
        }

        // chunk0 src loads for current node (8 x 16B per lane-row)
        bf16x8 af[4];
        load_convert(af, src + (size_t)ea * DIM + q * 8);

        if (hn) {                                 // prefetch next perm chunks
            int r02 = c2 < 16 ? c2 : 16;
            ea2 = (n < r02) ? perm[st2 + n] : 0;
            int r12 = (c2 > 16) ? ((c2 < 32 ? c2 : 32) - 16) : 0;
            eb2 = (n < r12) ? perm[st2 + 16 + n] : 0;
        }

        // R2 FIX: current node's chunk-1 valid-row count, recomputed per node
        const int r1c = (c > 16) ? ((c < 32 ? c : 32) - 16) : 0;

        float* orow = out + (size_t)node * DIM;
        if (c == 0) {                             // empty segment: -inf
            orow[lane]      = -INFINITY;
            orow[lane + 64] = -INFINITY;
        } else {
            floatx4 acc[8];
#pragma unroll
            for (int nb = 0; nb < 8; ++nb) acc[nb] = (floatx4)(0.0f);
            mfma_tile(af, Wl, acc, lane);

            if (c <= 16) {
                // mask invalid rows in place, then reduce
#pragma unroll
                for (int nb = 0; nb < 8; ++nb)
#pragma unroll
                    for (int r = 0; r < 4; ++r)
                        if (q * 4 + r >= c) acc[nb][r] = -INFINITY;
                reduce_store(acc, bias, orow, q, lane);
            } else {
                floatx4 vmax[8];
#pragma unroll
                for (int nb = 0; nb < 8; ++nb) vmax[nb] = acc[nb];  // 16 full rows

                // chunk1 (rows 16..min(c,32)), mask with CURRENT r1c
                bf16x8 af1[4];
                load_convert(af1, src + (size_t)eb * DIM + q * 8);
#pragma unroll
                for (int nb = 0; nb < 8; ++nb) acc[nb] = (floatx4)(0.0f);
                mfma_tile(af1, Wl, acc, lane);
#pragma unroll
                for (int nb = 0; nb < 8; ++nb)
#pragma unroll
                    for (int r = 0; r < 4; ++r) {
                        float v = (q * 4 + r < r1c) ? acc[nb][r] : -INFINITY;
                        vmax[nb][r] = fmaxf(vmax[nb][r], v);
                    }

                // rare tail: c > 32
                for (int base = 32; base < c; base += 16) {
                    int rr = c - base; if (rr > 16) rr = 16;
                    int e3 = (n < rr) ? perm[st + base + n] : 0;
                    bf16x8 af2[4];
                    load_convert(af2, src + (size_t)e3 * DIM + q * 8);
#pragma unroll
                    for (int nb = 0; nb < 8; ++nb) acc[nb] = (floatx4)(0.0f);
                    mfma_tile(af2, Wl, acc, lane);
#pragma unroll
                    for (int nb = 0; nb < 8; ++nb)
#pragma unroll
                        for (int r = 0; r < 4; ++r) {
                            float v = (q * 4 + r < rr) ? acc[nb][r] : -INFINITY;
                            vmax[nb][r] = fmaxf(vmax[nb][r], v);
                        }
                }
                reduce_store(vmax, bias, orow, q, lane);
            }
        }

        if (!hn) break;
        node = nnode; c = c2; st = st2; ea = ea2; eb = eb2;
    }
}

extern "C" void kernel_launch(void* const* d_in, const int* in_sizes, int n_in,
                              void* d_out, int out_size, void* d_ws, size_t ws_size,
                              hipStream_t stream) {
    const float* src  = (const float*)d_in[0];
    const float* W    = (const float*)d_in[1];
    const float* bias = (const float*)d_in[2];
    const int*   dst  = (const int*)d_in[3];
    // d_in[4] = n_nodes (scalar) — compile-time constant here.

    // workspace layout (total ~2.92 MB):
    char* ws = (char*)d_ws;
    __bf16* Wsw  = (__bf16*)ws;                      // 32768 B
    int* cnt     = (int*)(ws + 32768);               // 160000 B
    int* starts  = (int*)(ws + 32768 + 160000);      // 160000 B
    int* perm    = (int*)(ws + 32768 + 320000);      // 2560000 B
    float* outf  = (float*)d_out;

    // fused cooperative prep (zero+swizzle -> hist -> scan -> scatter)
    void* kargs[] = {(void*)&W, (void*)&dst, (void*)&Wsw,
                     (void*)&cnt, (void*)&starts, (void*)&perm};
    hipError_t cerr = hipLaunchCooperativeKernel((const void*)prep_all,
                                                 dim3(PREP_BLOCKS), dim3(256),
                                                 kargs, 0, stream);
    if (cerr != hipSuccess) {
        (void)hipGetLastError();   // clear sticky error; fall back to split prep
        prep_kernel<<<(N_NODES + 255) / 256, 256, 0, stream>>>(W, Wsw, cnt);
        hist_kernel<<<E_EDGES / 256, 256, 0, stream>>>(dst, cnt);
        scan_kernel<<<1, 1024, 0, stream>>>(cnt, starts);
        scatter_kernel<<<E_EDGES / 256, 256, 0, stream>>>(dst, starts, perm);
    }

    // persistent, atomic-free gather-GEMM + segmented max
    node_gemm_kernel<<<GEMM_BLOCKS, 256, 0, stream>>>(src, Wsw, bias, perm,
                                                      cnt, starts, outf);
}

// Round 5
// 602.978 us; speedup vs baseline: 1.6411x; 1.6411x over previous
//
#include <hip/hip_runtime.h>
#include <hip/hip_bf16.h>

// Problem constants (fixed by the reference):
#define E_EDGES 640000
#define DIM     128
#define N_NODES 40000

// Replicated-histogram counting sort: K edge-slices (r = e & 15) de-contend
// the global atomics (R3 post-mortem: 1.28M atomics on 2500 cache lines ran
// at ~0.004 atomics/ns; R0 showed 145/ns when spread over 320K lines).
#define KREP  16
#define HSIZE (KREP * N_NODES)

typedef __bf16 bf16x8 __attribute__((ext_vector_type(8)));
typedef float  floatx4 __attribute__((ext_vector_type(4)));

// ---------------------------------------------------------------------------
// W swizzle into bf16 B-fragment lane order:
// Wsw[((nb*4+kb)*64 + lane)*8 + j] = W[nb*16 + (lane&15)][kb*32 + (lane>>4)*8 + j]
// ---------------------------------------------------------------------------
__device__ __forceinline__ void swizzle_w(const float* __restrict__ W,
                                          __bf16* __restrict__ Wsw, int tid) {
    int lane = tid & 63;
    int kb   = (tid >> 6) & 3;
    int nb   = tid >> 8;
    int f    = nb * 16 + (lane & 15);
    int k0   = kb * 32 + ((lane >> 4) & 3) * 8;
    const float* wrow = W + f * DIM + k0;
    __bf16* o = Wsw + tid * 8;
#pragma unroll
    for (int j = 0; j < 8; ++j) o[j] = (__bf16)wrow[j];
}

// P0: zero replica histograms + swizzle W. grid = 2500 x 256 covers HSIZE.
__global__ void prep0_kernel(const float* __restrict__ W,
                             __bf16* __restrict__ Wsw,
                             int* __restrict__ H) {
    int tid = blockIdx.x * 256 + threadIdx.x;
    if (tid < HSIZE) H[tid] = 0;
    if (tid < 2048) swizzle_w(W, Wsw, tid);
}

// P1: replicated histogram. Slice r = e & 15 (deterministic; same in scatter).
__global__ void hist16_kernel(const int* __restrict__ dst, int* __restrict__ H) {
    int e = blockIdx.x * 256 + threadIdx.x;
    atomicAdd(&H[(e & (KREP - 1)) * N_NODES + dst[e]], 1);
}

// S1: cnt[n] = sum_r H[r][n] (16 coalesced passes) + per-block totals.
__global__ __launch_bounds__(256)
void sum_kernel(const int* __restrict__ H, int* __restrict__ cnt,
                int* __restrict__ bsum) {
    __shared__ int sred[256];
    int n = blockIdx.x * 256 + threadIdx.x;
    int s = 0;
    if (n < N_NODES) {
#pragma unroll
        for (int r = 0; r < KREP; ++r) s += H[r * N_NODES + n];
        cnt[n] = s;
    }
    sred[threadIdx.x] = s;
    __syncthreads();
    for (int off = 128; off > 0; off >>= 1) {
        if (threadIdx.x < off) sred[threadIdx.x] += sred[threadIdx.x + off];
        __syncthreads();
    }
    if (threadIdx.x == 0) bsum[blockIdx.x] = sred[0];
}

// S2: exclusive scan of the 160 block totals (single tiny block).
__global__ __launch_bounds__(256)
void scanb_kernel(const int* __restrict__ bsum, int* __restrict__ bstart) {
    __shared__ int ss[256];
    int t = threadIdx.x;
    int v = (t < 160) ? bsum[t] : 0;
    int orig = v;
    ss[t] = v;
    __syncthreads();
    for (int off = 1; off < 256; off <<= 1) {
        int u = (t >= off) ? ss[t - off] : 0;
        __syncthreads();
        ss[t] += u;
        __syncthreads();
    }
    if (t < 160) bstart[t] = ss[t] - orig;
}

// S3: per-block exclusive scan -> starts[n]; then overwrite H[r][n] with the
// replica's pre-assigned output cursor (in-place, coalesced per r-pass).
__global__ __launch_bounds__(256)
void offs_kernel(int* __restrict__ H, const int* __restrict__ cnt,
                 const int* __restrict__ bstart, int* __restrict__ starts) {
    __shared__ int ss[256];
    int t = threadIdx.x;
    int n = blockIdx.x * 256 + t;
    int v = (n < N_NODES) ? cnt[n] : 0;
    int orig = v;
    ss[t] = v;
    __syncthreads();
    for (int off = 1; off < 256; off <<= 1) {
        int u = (t >= off) ? ss[t - off] : 0;
        __syncthreads();
        ss[t] += u;
        __syncthreads();
    }
    if (n < N_NODES) {
        int run = bstart[blockIdx.x] + ss[t] - orig;
        starts[n] = run;
#pragma unroll
        for (int r = 0; r < KREP; ++r) {
            int idx = r * N_NODES + n;
            int h = H[idx];
            H[idx] = run;
            run += h;
        }
    }
}

// P2: scatter. Each replica bumps only its own pre-assigned cursor range, so
// contention per address = same-slice same-node edges (~1 on average).
__global__ void scatter16_kernel(const int* __restrict__ dst,
                                 int* __restrict__ H, int* __restrict__ perm) {
    int e = blockIdx.x * 256 + threadIdx.x;
    int pos = atomicAdd(&H[(e & (KREP - 1)) * N_NODES + dst[e]], 1);
    perm[pos] = e;
}

// --------------------- fallback (small-ws) prep: R1 path -------------------
__global__ void prep_kernel(const float* __restrict__ W,
                            __bf16* __restrict__ Wsw,
                            int* __restrict__ cnt) {
    int tid = blockIdx.x * blockDim.x + threadIdx.x;
    if (tid < N_NODES) cnt[tid] = 0;
    if (tid < 2048) swizzle_w(W, Wsw, tid);
}
__global__ void hist_kernel(const int* __restrict__ dst, int* __restrict__ cnt) {
    int e = blockIdx.x * 256 + threadIdx.x;
    atomicAdd(&cnt[dst[e]], 1);
}
__global__ __launch_bounds__(1024)
void scan_kernel(const int* __restrict__ cnt, int* __restrict__ starts) {
    __shared__ int ss[1024];
    const int t = threadIdx.x;
    const int base = t * 40;
    int local = 0;
    for (int i = 0; i < 40; ++i) {
        int idx = base + i;
        if (idx < N_NODES) local += cnt[idx];
    }
    ss[t] = local;
    __syncthreads();
    for (int off = 1; off < 1024; off <<= 1) {
        int v = (t >= off) ? ss[t - off] : 0;
        __syncthreads();
        ss[t] += v;
        __syncthreads();
    }
    int run = ss[t] - local;
    for (int i = 0; i < 40; ++i) {
        int idx = base + i;
        if (idx < N_NODES) { starts[idx] = run; run += cnt[idx]; }
    }
}
__global__ void scatter_kernel(const int* __restrict__ dst,
                               int* __restrict__ starts,
                               int* __restrict__ perm) {
    int e = blockIdx.x * 256 + threadIdx.x;
    int pos = atomicAdd(&starts[dst[e]], 1);
    perm[pos] = e;
}

// ---------------------------------------------------------------------------
// Main kernel (R1's measured-202µs form, verbatim structure). One wave per
// node, 16-row MFMA chunks, running register max, zero atomics, one coalesced
// 512B store per node. st_mode: 0 -> stends = unbumped starts (main path);
// 1 -> stends = bumped-to-end starts (fallback path), st = stends - c.
// A-frag:  A[m=lane&15][k=q*8+j]   (gathered rows, 16B loads)
// B-frag:  B[k=q*8+j][n=lane&15]   (pre-swizzled, staged in LDS per block)
// C/D:     col=lane&15, row=q*4+reg
// ---------------------------------------------------------------------------
__global__ __launch_bounds__(256)
void node_gemm_kernel(const float* __restrict__ src,
                      const __bf16* __restrict__ Wsw,
                      const float* __restrict__ bias,
                      const int* __restrict__ perm,
                      const int* __restrict__ cnt,
                      const int* __restrict__ stends,
                      float* __restrict__ out, int st_mode) {
    __shared__ bf16x8 Wl[2048];   // 32 KB swizzled W, shared by 4 waves
    const int t = threadIdx.x;
    {
        const float4* gw = (const float4*)Wsw;
        float4* lw = (float4*)Wl;
#pragma unroll
        for (int i = 0; i < 8; ++i) lw[t + i * 256] = gw[t + i * 256];
    }
    __syncthreads();

    const int lane = t & 63;
    const int wave = t >> 6;
    const int q    = lane >> 4;
    const int n    = lane & 15;
    const int node = blockIdx.x * 4 + wave;

    const int c  = cnt[node];
    const int se = stends[node];
    const int st = st_mode ? (se - c) : se;
    float* orow = out + (size_t)node * DIM;

    if (c == 0) {   // empty segment: -inf, matching jax segment_max
        orow[lane]      = -INFINITY;
        orow[lane + 64] = -INFINITY;
        return;
    }

    floatx4 vmax[8];
#pragma unroll
    for (int nb = 0; nb < 8; ++nb) vmax[nb] = (floatx4)(-INFINITY);

    const int nch = (c + 15) >> 4;
    for (int ch = 0; ch < nch; ++ch) {
        int rows = c - (ch << 4);
        if (rows > 16) rows = 16;
        int e = (n < rows) ? perm[st + (ch << 4) + n] : 0;
        const float* arow = src + (size_t)e * DIM + q * 8;

        floatx4 acc[8];
#pragma unroll
        for (int nb = 0; nb < 8; ++nb) acc[nb] = (floatx4)(0.0f);

#pragma unroll
        for (int kb = 0; kb < 4; ++kb) {
            float4 a0 = *(const float4*)(arow + kb * 32);
            float4 a1 = *(const float4*)(arow + kb * 32 + 4);
            bf16x8 af;
            af[0] = (__bf16)a0.x; af[1] = (__bf16)a0.y;
            af[2] = (__bf16)a0.z; af[3] = (__bf16)a0.w;
            af[4] = (__bf16)a1.x; af[5] = (__bf16)a1.y;
            af[6] = (__bf16)a1.z; af[7] = (__bf16)a1.w;
#pragma unroll
            for (int nb = 0; nb < 8; ++nb) {
                bf16x8 bf = Wl[(nb * 4 + kb) * 64 + lane];
                acc[nb] = __builtin_amdgcn_mfma_f32_16x16x32_bf16(af, bf, acc[nb], 0, 0, 0);
            }
        }

#pragma unroll
        for (int nb = 0; nb < 8; ++nb)
#pragma unroll
            for (int r = 0; r < 4; ++r) {
                float v = (q * 4 + r < rows) ? acc[nb][r] : -INFINITY;
                vmax[nb][r] = fmaxf(vmax[nb][r], v);
            }
    }

    float red[8];
#pragma unroll
    for (int nb = 0; nb < 8; ++nb) {
        float v = fmaxf(fmaxf(vmax[nb][0], vmax[nb][1]),
                        fmaxf(vmax[nb][2], vmax[nb][3]));
        v = fmaxf(v, __shfl_xor(v, 16));
        v = fmaxf(v, __shfl_xor(v, 32));
        red[nb] = v;
    }
    float o1 = (q == 0) ? red[0] : (q == 1) ? red[1] : (q == 2) ? red[2] : red[3];
    float o2 = (q == 0) ? red[4] : (q == 1) ? red[5] : (q == 2) ? red[6] : red[7];
    // bias-add and relu commute with max (bias per-column, relu monotone)
    orow[lane]      = fmaxf(o1 + bias[lane],      0.0f);
    orow[lane + 64] = fmaxf(o2 + bias[lane + 64], 0.0f);
}

extern "C" void kernel_launch(void* const* d_in, const int* in_sizes, int n_in,
                              void* d_out, int out_size, void* d_ws, size_t ws_size,
                              hipStream_t stream) {
    const float* src  = (const float*)d_in[0];
    const float* W    = (const float*)d_in[1];
    const float* bias = (const float*)d_in[2];
    const int*   dst  = (const int*)d_in[3];
    // d_in[4] = n_nodes (scalar) — compile-time constant here.

    // workspace layout:
    //   Wsw 32768 | cnt 160000 | starts 160000 | perm 2560000 |
    //   bsum 1024 | bstart 1024 | H 2560000      -> total 5,474,816 B
    char* ws = (char*)d_ws;
    size_t off = 0;
    __bf16* Wsw  = (__bf16*)(ws + off); off += 32768;
    int* cnt     = (int*)(ws + off);    off += 160000;
    int* starts  = (int*)(ws + off);    off += 160000;
    int* perm    = (int*)(ws + off);    off += 2560000;
    int* bsum    = (int*)(ws + off);    off += 1024;
    int* bstart  = (int*)(ws + off);    off += 1024;
    int* H       = (int*)(ws + off);    off += (size_t)HSIZE * 4;
    float* outf  = (float*)d_out;

    if (ws_size >= off) {
        // de-contended counting sort (replicated histograms, K=16)
        prep0_kernel<<<2500, 256, 0, stream>>>(W, Wsw, H);
        hist16_kernel<<<E_EDGES / 256, 256, 0, stream>>>(dst, H);
        sum_kernel<<<160, 256, 0, stream>>>(H, cnt, bsum);
        scanb_kernel<<<1, 256, 0, stream>>>(bsum, bstart);
        offs_kernel<<<160, 256, 0, stream>>>(H, cnt, bstart, starts);
        scatter16_kernel<<<E_EDGES / 256, 256, 0, stream>>>(dst, H, perm);
        node_gemm_kernel<<<N_NODES / 4, 256, 0, stream>>>(src, Wsw, bias, perm,
                                                          cnt, starts, outf, 0);
    } else {
        // fallback: R1's contended-atomic path (correct, slower)
        prep_kernel<<<(N_NODES + 255) / 256, 256, 0, stream>>>(W, Wsw, cnt);
        hist_kernel<<<E_EDGES / 256, 256, 0, stream>>>(dst, cnt);
        scan_kernel<<<1, 1024, 0, stream>>>(cnt, starts);
        scatter_kernel<<<E_EDGES / 256, 256, 0, stream>>>(dst, starts, perm);
        node_gemm_kernel<<<N_NODES / 4, 256, 0, stream>>>(src, Wsw, bias, perm,
                                                          cnt, starts, outf, 1);
    }
}